// Round 18
// baseline (510.490 us; speedup 1.0000x reference)
//
#include <hip/hip_runtime.h>
#include <stdint.h>

// KronQRInjectedLinear: out = ((input @ rot) @ Q) @ R_eff.
// Kron structure: rot via batched T@Q1^T; D via De/Do with split-K (r15/16).
// GEMM core v9b: 256x128 tile, 8 waves (4Mx2N, wave 64x64), BK=32 chunks in
// 3 rotating buffers (72 KB LDS -> TWO blocks per CU; grids all 512 blocks).
// FIX vs r17: staging inverse now matches the 16x16 pair-packed read layout
// (rule 21 both-sides-or-neither; r17 paired the r8 32x32 inverse = garbage).
// Phases: 8 ds_read + 3 gloads -> barrier -> lgkm(0) -> 16 MFMA -> vmcnt(3) -> barrier.

typedef unsigned short u16;
typedef short bf16x8 __attribute__((ext_vector_type(8)));
typedef float f32x4 __attribute__((ext_vector_type(4)));

__device__ __forceinline__ u16 f2bf(float f) {
  union { float f; uint32_t u; } v; v.f = f;
  return (u16)((v.u + 0x7FFFu + ((v.u >> 16) & 1u)) >> 16);
}

__device__ __forceinline__ void store_out(float* p, float v) { *p = v; }
__device__ __forceinline__ void store_out(u16* p, float v) { *p = f2bf(v); }

__device__ __forceinline__ void gload_lds16(const u16* g, u16* l) {
  __builtin_amdgcn_global_load_lds(
      (__attribute__((address_space(1))) void*)(uintptr_t)g,
      (__attribute__((address_space(3))) void*)l, 16, 0, 0);
}

#define MFMA16(a, b, c) __builtin_amdgcn_mfma_f32_16x16x32_bf16((a), (b), (c), 0, 0, 0)

// -------- GEMM: C[M,N] = A[M,K] @ Bt[N,K]^T (batched: A += z*sA, Bt += (z>>1)*sB) --------
// LDS piece (4096 elems) = 128 rows x 32 kk, pair-packed:
//   elem (rp,kk) -> (rp>>1)*64 + (((kk>>3)+4*(rp&1)) ^ ((rp>>1)&7))*8 + (kk&7)
// A buf = 2 pieces (rh), B buf = 1 piece; 3 bufs each. Read frag f=0..7 of a piece:
//   lane l -> f*512 + ((l&15)>>1)*64 + (((l>>4)+4*(l&1)) ^ ((l&15)>>1))*8   [proven 0-conflict]
template <typename OutT>
__global__ __launch_bounds__(512, 4) void gemm256(
    const u16* __restrict__ A, const u16* __restrict__ Bt, OutT* __restrict__ C,
    int M, int N, int K, int ldC, long long sA, long long sB, long long sC) {
  extern __shared__ __align__(16) u16 smem[];
  u16* ldsA = smem;            // 3 bufs x 8192 elems (48 KB)
  u16* ldsB = smem + 24576;    // 3 bufs x 4096 elems (24 KB)

  const int tid  = (int)threadIdx.x;
  const int lane = tid & 63;
  const int wid  = tid >> 6;
  const int wr   = wid >> 1;       // 0..3 : M quarter (64 rows)
  const int wc   = wid & 1;        // 0..1 : N half (64 cols)

  // XCD-aware bijective swizzle (nwg % 8 == 0 for all our grids)
  const int tilesX = (int)gridDim.x;
  const int tilesXY = tilesX * (int)gridDim.y;
  const int nwg = tilesXY * (int)gridDim.z;
  const int bid = ((int)blockIdx.z * (int)gridDim.y + (int)blockIdx.y) * tilesX + (int)blockIdx.x;
  const int swz = (bid & 7) * (nwg >> 3) + (bid >> 3);
  const int z   = swz / tilesXY;
  const int rem = swz % tilesXY;
  const int brow = (rem / tilesX) << 8;   // 256-row tiles
  const int bcol = (rem % tilesX) << 7;   // 128-col tiles
  A += (size_t)z * sA;
  Bt += (size_t)(z >> 1) * sB;
  C += (size_t)z * sC;

  // fragment-read lane constants (proven 0-conflict function)
  const int lr = lane & 15, lg = lane >> 4, h = lr >> 1;
  const int sf = (lg + ((lr & 1) << 2)) ^ h;
  const int abase = (wr >> 1) * 4096 + (wr & 1) * 2048 + h * 64 + sf * 8;  // + m*512
  const int bbase = wc * 2048 + h * 64 + sf * 8;                          // + n*512

  // staging: linear LDS dest (wid*512 elems within piece); inverse of the
  // pair-packed layout (r16-proven): kp = slot^h -> p = kp>>2, kk-block = kp&3.
  const int kp   = (tid & 7) ^ ((tid >> 3) & 7);
  const int srow = 2 * (tid >> 3) + (kp >> 2);
  const int scol = (kp & 3) << 3;
  const size_t gA0 = (size_t)(brow + srow) * K + scol;
  const size_t gB0 = (size_t)(bcol + srow) * K + scol;
  const size_t rstep = (size_t)K << 7;     // 128 rows (piece stride in A)
  const int sdst = wid * 512;

  const int NC = K >> 5;                   // 32-wide chunks; NC >= 3

  f32x4 acc[4][4] = {};
  bf16x8 af[4], bf[4];

  // rotating buffer offsets (elems): cur (read), nxt (in flight), spr (stage target)
  int aCur = 0, aNxt = 8192, aSpr = 16384;
  int bCur = 0, bNxt = 4096, bSpr = 8192;

#define STG_A(c, rh, dstOff) gload_lds16(A + gA0 + (rh) * rstep + (size_t)(c) * 32, \
    ldsA + (dstOff) + (rh) * 4096 + sdst)
#define STG_B(c, dstOff) gload_lds16(Bt + gB0 + (size_t)(c) * 32, ldsB + (dstOff) + sdst)
#define STAGE(c, aOff, bOff) do { STG_A(c, 0, aOff); STG_A(c, 1, aOff); STG_B(c, bOff); } while (0)
#define VM3 asm volatile("s_waitcnt vmcnt(3)" ::: "memory")
#define VM0 asm volatile("s_waitcnt vmcnt(0)" ::: "memory")

  // Prologue: stage chunks 0 (->buf0), 1 (->buf1); complete chunk 0 (leave 1 in flight).
  STAGE(0, 0, 0);
  STAGE(1, 8192, 4096);
  VM3;
  __builtin_amdgcn_sched_barrier(0);
  __builtin_amdgcn_s_barrier();

  // Phase c: read chunk c (8 ds_read_b128), stage c+2 into spare, 16 MFMA.
#define PH(DOSTG, c2, TAIL) do {                                                \
    const u16* _pa = ldsA + aCur + abase;                                       \
    const u16* _pb = ldsB + bCur + bbase;                                       \
    _Pragma("unroll")                                                           \
    for (int m = 0; m < 4; ++m) af[m] = *(const bf16x8*)(_pa + m * 512);        \
    _Pragma("unroll")                                                           \
    for (int n = 0; n < 4; ++n) bf[n] = *(const bf16x8*)(_pb + n * 512);        \
    if (DOSTG) STAGE(c2, aSpr, bSpr);                                           \
    __builtin_amdgcn_s_barrier();                                               \
    asm volatile("s_waitcnt lgkmcnt(0)" ::: "memory");                          \
    __builtin_amdgcn_sched_barrier(0);                                          \
    __builtin_amdgcn_s_setprio(1);                                              \
    _Pragma("unroll")                                                           \
    for (int m = 0; m < 4; ++m)                                                 \
      _Pragma("unroll")                                                         \
      for (int n = 0; n < 4; ++n)                                               \
        acc[m][n] = MFMA16(af[m], bf[n], acc[m][n]);                            \
    __builtin_amdgcn_s_setprio(0);                                              \
    TAIL;                                                                       \
    __builtin_amdgcn_sched_barrier(0);                                          \
    __builtin_amdgcn_s_barrier();                                               \
    const int _ta = aCur; aCur = aNxt; aNxt = aSpr; aSpr = _ta;                 \
    const int _tb = bCur; bCur = bNxt; bNxt = bSpr; bSpr = _tb;                 \
  } while (0)

  // Main: phases 0..NC-3 stage c+2 and keep 2 chunks (6 loads) in flight.
  for (int c = 0; c < NC - 2; ++c) PH(1, c + 2, VM3);
  PH(0, 0, VM0);    // phase NC-2: drain last chunk
  PH(0, 0, (void)0);// phase NC-1

#undef PH
#undef STAGE
#undef STG_A
#undef STG_B
#undef VM3
#undef VM0

  // C/D layout per 16x16 frag: col = lane&15, row = (lane>>4)*4 + j
#pragma unroll
  for (int m = 0; m < 4; ++m) {
    const int r0 = brow + wr * 64 + m * 16 + lg * 4;
#pragma unroll
    for (int n = 0; n < 4; ++n) {
      const int cc = bcol + wc * 64 + n * 16 + lr;
#pragma unroll
      for (int j = 0; j < 4; ++j)
        store_out(&C[(size_t)(r0 + j) * ldC + cc], acc[m][n][j]);
    }
  }
}

// ---------------- tiled transpose: out[c][r] = bf16(in[r][c]) ----------------
__global__ void trans_kernel(const float* __restrict__ in, u16* __restrict__ out, int n) {
  __shared__ float t[32][33];
  const int bx = (int)blockIdx.x * 32, by = (int)blockIdx.y * 32;
  const int x = (int)threadIdx.x, y0 = (int)threadIdx.y;
#pragma unroll
  for (int dy = 0; dy < 32; dy += 8)
    t[y0 + dy][x] = in[(size_t)(bx + y0 + dy) * n + by + x];
  __syncthreads();
#pragma unroll
  for (int dy = 0; dy < 32; dy += 8)
    out[(size_t)(by + y0 + dy) * n + bx + x] = f2bf(t[x][y0 + dy]);
}

// Qtp[c][perm(r)] = bf16(Q[r][c]); perm(r) = ((r&1)<<11)|(r>>1)
__global__ void transperm_kernel(const float* __restrict__ in, u16* __restrict__ out) {
  __shared__ float t[32][33];
  const int bx = (int)blockIdx.x * 32, by = (int)blockIdx.y * 32;
  const int x = (int)threadIdx.x, y0 = (int)threadIdx.y;
#pragma unroll
  for (int dy = 0; dy < 32; dy += 8)
    t[y0 + dy][x] = in[(size_t)(bx + y0 + dy) * 4096 + by + x];
  __syncthreads();
  const int r = bx + x;
  const int cp = ((r & 1) << 11) | (r >> 1);
#pragma unroll
  for (int dy = 0; dy < 32; dy += 8)
    out[(size_t)(by + y0 + dy) * 4096 + cp] = f2bf(t[x][y0 + dy]);
}

// rteff[i][j] = bf16(R[j][i] + D[i][j]);
// D[i][j] = c0(i,j)*(Dsub0+Dsub2)[i>>1][j>>1] + c1(i,j)*(Dsub1+Dsub3)[i>>1][j>>1]
__global__ void transadd_kernel(const float* __restrict__ R, const float* __restrict__ Dsub,
                                const float* __restrict__ R2, u16* __restrict__ out) {
  __shared__ float t[32][33];
  const int bx = (int)blockIdx.x * 32, by = (int)blockIdx.y * 32;
  const int x = (int)threadIdx.x, y0 = (int)threadIdx.y;
#pragma unroll
  for (int dy = 0; dy < 32; dy += 8)
    t[y0 + dy][x] = R[(size_t)(bx + y0 + dy) * 4096 + by + x];
  __syncthreads();
  const float r20 = R2[0], r21 = R2[1], r22 = R2[2], r23 = R2[3];
  const int j = bx + x;
  const float cj0 = (j & 1) ? r22 : r20;   // R2[j2][0]
  const float cj1 = (j & 1) ? r23 : r21;   // R2[j2][1]
#pragma unroll
  for (int dy = 0; dy < 32; dy += 8) {
    const int i = by + y0 + dy;
    const float ci0 = (i & 1) ? r22 : r20;
    const float ci1 = (i & 1) ? r23 : r21;
    const size_t o = ((size_t)(i >> 1) << 11) + (j >> 1);
    const float de = Dsub[o] + Dsub[o + 2u * 4194304u];
    const float dd = Dsub[o + 4194304u] + Dsub[o + 3u * 4194304u];
    const float d = ci0 * cj0 * de + ci1 * cj1 * dd;
    out[(size_t)i * 4096 + j] = f2bf(t[x][y0 + dy] + d);
  }
}

// Split-K layout: B2[kh][i1][kk] = bf16(R1[i1][kh*1024+kk]);
// A4[kh*2+p][i1][kk] = bf16(R1 .* lam_{e/o}) for parity p.
__global__ void scale_r1_kernel(const float* __restrict__ R1, const float* __restrict__ lam,
                                u16* __restrict__ B2, u16* __restrict__ A4) {
  const int idx = (int)blockIdx.x * 256 + (int)threadIdx.x;   // over 2048*512
  const int i1 = idx >> 9, k1 = (idx & 511) << 2;
  const float4 r1 = *(const float4*)(R1 + (size_t)i1 * 2048 + k1);
  const float4 l0 = *(const float4*)(lam + 2 * k1);
  const float4 l1 = *(const float4*)(lam + 2 * k1 + 4);
  const int kh = k1 >> 10, kk = k1 & 1023;
  const size_t off = (size_t)i1 * 1024 + kk;
  const size_t P = 2097152;   // plane elems (2048*1024)
  ushort4 rb, eb, ob;
  rb.x = f2bf(r1.x); rb.y = f2bf(r1.y); rb.z = f2bf(r1.z); rb.w = f2bf(r1.w);
  eb.x = f2bf(r1.x * l0.x); eb.y = f2bf(r1.y * l0.z);
  eb.z = f2bf(r1.z * l1.x); eb.w = f2bf(r1.w * l1.z);
  ob.x = f2bf(r1.x * l0.y); ob.y = f2bf(r1.y * l0.w);
  ob.z = f2bf(r1.z * l1.y); ob.w = f2bf(r1.w * l1.w);
  *(ushort4*)(B2 + (size_t)kh * P + off) = rb;
  *(ushort4*)(A4 + (size_t)(kh * 2) * P + off) = eb;
  *(ushort4*)(A4 + (size_t)(kh * 2 + 1) * P + off) = ob;
}

// T[j2][s][k1] = bf16(in[s][2k1]*Q2[0][j2] + in[s][2k1+1]*Q2[1][j2])
__global__ void tprep_kernel(const float* __restrict__ in, const float* __restrict__ Q2,
                             u16* __restrict__ T) {
  const int idx = (int)blockIdx.x * 256 + (int)threadIdx.x;   // over 4096*512
  const int s = idx >> 9, k1 = (idx & 511) << 2;
  const float4 a = *(const float4*)(in + (size_t)s * 4096 + 2 * k1);
  const float4 b = *(const float4*)(in + (size_t)s * 4096 + 2 * k1 + 4);
  const float e[4] = {a.x, a.z, b.x, b.z};
  const float o[4] = {a.y, a.w, b.y, b.w};
  const float q00 = Q2[0], q01 = Q2[1], q10 = Q2[2], q11 = Q2[3];
  ushort4 t0, t1;
  t0.x = f2bf(e[0] * q00 + o[0] * q10); t1.x = f2bf(e[0] * q01 + o[0] * q11);
  t0.y = f2bf(e[1] * q00 + o[1] * q10); t1.y = f2bf(e[1] * q01 + o[1] * q11);
  t0.z = f2bf(e[2] * q00 + o[2] * q10); t1.z = f2bf(e[2] * q01 + o[2] * q11);
  t0.w = f2bf(e[3] * q00 + o[3] * q10); t1.w = f2bf(e[3] * q01 + o[3] * q11);
  *(ushort4*)(T + (size_t)s * 2048 + k1) = t0;
  *(ushort4*)(T + 8388608 + (size_t)s * 2048 + k1) = t1;
}

extern "C" void kernel_launch(void* const* d_in, const int* in_sizes, int n_in,
                              void* d_out, int out_size, void* d_ws, size_t ws_size,
                              hipStream_t stream) {
  const float* input = (const float*)d_in[0];
  const float* Q     = (const float*)d_in[1];
  const float* R     = (const float*)d_in[2];
  const float* Q1    = (const float*)d_in[3];
  const float* Q2    = (const float*)d_in[4];
  const float* R1    = (const float*)d_in[5];
  const float* R2    = (const float*)d_in[6];
  const float* lam   = (const float*)d_in[7];
  float* out = (float*)d_out;

  const size_t MB = 1024ull * 1024ull;
  char* ws = (char*)d_ws;
  u16* B2    = (u16*)(ws + 0 * MB);     // 2 planes [2048][1024] bf16 (8MB)
  u16* A4    = (u16*)(ws + 8 * MB);     // 4 planes [2048][1024] bf16 (16MB)
  u16* Q1tb  = (u16*)(ws + 24 * MB);
  u16* T     = (u16*)(ws + 32 * MB);    // 2 planes of 16MB
  u16* Qtp   = (u16*)(ws + 64 * MB);
  u16* rteff = (u16*)(ws + 96 * MB);
  u16* X1p   = (u16*)(ws + 128 * MB);   // needs ws_size >= 160 MB
  u16* X2    = (u16*)(ws + 8 * MB);     // reuses A4/Q1tb/T-head (all dead by step 8)
  float* Dsub = (float*)d_out;          // 4 x 2048^2 f32 (64MB), consumed by transadd

  {
    void (*pf)(const u16*, const u16*, float*, int, int, int, int, long long, long long, long long) = gemm256<float>;
    void (*pb)(const u16*, const u16*, u16*, int, int, int, int, long long, long long, long long)   = gemm256<u16>;
    (void)hipFuncSetAttribute((const void*)pf, hipFuncAttributeMaxDynamicSharedMemorySize, 73728);
    (void)hipFuncSetAttribute((const void*)pb, hipFuncAttributeMaxDynamicSharedMemorySize, 73728);
  }

  const dim3 tb(32, 8);
  // 1) Q1tb = bf16(Q1^T)
  trans_kernel<<<dim3(64, 64), tb, 0, stream>>>(Q1, Q1tb, 2048);
  // 2) Qtp = permuted bf16(Q^T)
  transperm_kernel<<<dim3(128, 128), tb, 0, stream>>>(Q, Qtp);
  // 3) B2 + A4 split-K scaled copies
  scale_r1_kernel<<<4096, 256, 0, stream>>>(R1, lam, B2, A4);
  // 4) T[j2] = Q2-contraction of input
  tprep_kernel<<<8192, 256, 0, stream>>>(input, Q2, T);
  // 5) Dsub[z] = A4[z] @ B2[z>>1]^T   (split-K batched 4x, 512 blocks = 2/CU)
  gemm256<float><<<dim3(16, 8, 4), 512, 73728, stream>>>(
      A4, B2, Dsub, 2048, 2048, 1024, 2048, 2097152LL, 2097152LL, 4194304LL);
  // 6) rteff = R^T + (c0*(D0+D2) + c1*(D1+D3) expanded via kron indices)
  transadd_kernel<<<dim3(128, 128), tb, 0, stream>>>(R, Dsub, R2, rteff);
  // 7) X1p[:, j2*2048+j1] = T[j2] @ Q1tb^T   (batched 2x, 512 blocks)
  gemm256<u16><<<dim3(16, 16, 2), 512, 73728, stream>>>(
      T, Q1tb, X1p, 4096, 2048, 2048, 4096, 8388608LL, 0LL, 2048LL);
  // 8) X2 = X1p @ Qtp^T   (4096^3, 512 blocks)
  gemm256<u16><<<dim3(32, 16, 1), 512, 73728, stream>>>(
      X1p, Qtp, X2, 4096, 4096, 4096, 4096, 0LL, 0LL, 0LL);
  // 9) out = X2 @ rteff^T  (4096^3, f32, 512 blocks)
  gemm256<float><<<dim3(32, 16, 1), 512, 73728, stream>>>(
      X2, rteff, out, 4096, 4096, 4096, 4096, 0LL, 0LL, 0LL);
}

// Round 19
// 432.826 us; speedup vs baseline: 1.1794x; 1.1794x over previous
//
#include <hip/hip_runtime.h>
#include <stdint.h>

// KronQRInjectedLinear: out = ((input @ rot) @ Q) @ R_eff.
// Kron structure: rot via 2x4096x2048x2048 batched; D via TWO 2048^3 GEMMs (De/Do)
// with split-K z=4 (full 256-CU grid), partials summed in transadd (r15).
// GEMM core: r5 8-phase BK=64 2-dbuf schedule with K-SLICE BALANCED PHASES
// (8/8/4/4 ds_reads) -- measured best (r16: 431.0 us total, 119.5 us @4096^3).
// r17/r18 (256x128 2-blocks/CU) regressed: FETCH 147->269 MB, reverted.

typedef unsigned short u16;
typedef short bf16x8 __attribute__((ext_vector_type(8)));
typedef float f32x4 __attribute__((ext_vector_type(4)));

__device__ __forceinline__ u16 f2bf(float f) {
  union { float f; uint32_t u; } v; v.f = f;
  return (u16)((v.u + 0x7FFFu + ((v.u >> 16) & 1u)) >> 16);
}

__device__ __forceinline__ void store_out(float* p, float v) { *p = v; }
__device__ __forceinline__ void store_out(u16* p, float v) { *p = f2bf(v); }

__device__ __forceinline__ void gload_lds16(const u16* g, u16* l) {
  __builtin_amdgcn_global_load_lds(
      (__attribute__((address_space(1))) void*)(uintptr_t)g,
      (__attribute__((address_space(3))) void*)l, 16, 0, 0);
}

#define MFMA16(a, b, c) __builtin_amdgcn_mfma_f32_16x16x32_bf16((a), (b), (c), 0, 0, 0)

// -------- GEMM: C[M,N] = A[M,K] @ Bt[N,K]^T (batched: A += z*sA, Bt += (z>>1)*sB) --------
template <typename OutT>
__global__ __launch_bounds__(512, 2) void gemm256(
    const u16* __restrict__ A, const u16* __restrict__ Bt, OutT* __restrict__ C,
    int M, int N, int K, int ldC, long long sA, long long sB, long long sC) {
  extern __shared__ __align__(16) u16 smem[];
  u16* ldsA = smem;           // 2 bufs x 16384 elems (64 KB)
  u16* ldsB = smem + 32768;

  const int tid  = (int)threadIdx.x;
  const int lane = tid & 63;
  const int wid  = tid >> 6;
  const int wr   = wid >> 2;       // 0..1 : M half (128 rows)
  const int wc   = wid & 3;        // 0..3 : N quarter (64 cols)

  // XCD-aware bijective swizzle (nwg % 8 == 0 for all our grids)
  const int tilesX = (int)gridDim.x;
  const int tilesXY = tilesX * (int)gridDim.y;
  const int nwg = tilesXY * (int)gridDim.z;
  const int bid = ((int)blockIdx.z * (int)gridDim.y + (int)blockIdx.y) * tilesX + (int)blockIdx.x;
  const int swz = (bid & 7) * (nwg >> 3) + (bid >> 3);
  const int z   = swz / tilesXY;
  const int rem = swz % tilesXY;
  const int brow = (rem / tilesX) << 8;
  const int bcol = (rem % tilesX) << 8;
  A += (size_t)z * sA;
  Bt += (size_t)(z >> 1) * sB;
  C += (size_t)z * sC;

  // fragment-read lane constants (swizzled 16B slot is lane-constant)
  const int lr = lane & 15, lg = lane >> 4, h = lr >> 1;
  const int sf = (lg + ((lr & 1) << 2)) ^ h;
  const int abase = wr * 8192 + h * 64 + sf * 8;                    // + frag*512 + ks*4096 + buf*16384
  const int bbase = (wc >> 1) * 8192 + ((wc & 1) * 32 + h) * 64 + sf * 8;

  // staging: linear LDS dest (tid*16B within 8KB piece), inverse-swizzled source
  const int kp   = (tid & 7) ^ ((tid >> 3) & 7);
  const int srow = 2 * (tid >> 3) + (kp >> 2);
  const int scol = (kp & 3) << 3;
  const size_t gA0 = (size_t)(brow + srow) * K + scol;
  const size_t gB0 = (size_t)(bcol + srow) * K + scol;
  const size_t rstep = (size_t)K << 7;     // 128 rows
  const int sdst = wid * 512;

  const int NC = K >> 6;                   // 64-wide K-tiles (even, >= 4)
  const int NI = NC >> 1;

  f32x4 acc[8][4] = {};
  bf16x8 af[4], bf[4][2];

#define STG_A(t, rh, ks) gload_lds16(A + gA0 + (rh) * rstep + (size_t)(t) * 64 + (ks) * 32, \
    ldsA + ((t) & 1) * 16384 + (rh) * 8192 + (ks) * 4096 + sdst)
#define STG_B(t, rh, ks) gload_lds16(Bt + gB0 + (rh) * rstep + (size_t)(t) * 64 + (ks) * 32, \
    ldsB + ((t) & 1) * 16384 + (rh) * 8192 + (ks) * 4096 + sdst)
#define VM4 asm volatile("s_waitcnt vmcnt(4)" ::: "memory")
#define VM0 asm volatile("s_waitcnt vmcnt(0)" ::: "memory")

  // Phase (BUF, MH, KS): read af[m][KS] m=MH*4..+3 (4) and, if RDBF, bf[n][KS] (4)
  // + 2 staged pieces -> barrier -> lgkm(0) -> 16 MFMA -> tail -> barrier.
  // Max 8 ds_reads per phase; bf[.][KS] persists from MH0 phases to MH1 phases.
#define PH(BUF, MH, KS, RDBF, S0, S1, TAIL) do {                                \
    const u16* _pa = ldsA + (BUF) * 16384 + abase + (KS) * 4096;                \
    const u16* _pb = ldsB + (BUF) * 16384 + bbase + (KS) * 4096;                \
    _Pragma("unroll")                                                           \
    for (int m = 0; m < 4; ++m)                                                 \
      af[m] = *(const bf16x8*)(_pa + ((MH) * 4 + m) * 512);                     \
    if (RDBF) {                                                                 \
      _Pragma("unroll")                                                         \
      for (int n = 0; n < 4; ++n)                                               \
        bf[n][KS] = *(const bf16x8*)(_pb + n * 512);                            \
    }                                                                           \
    S0; S1;                                                                     \
    __builtin_amdgcn_s_barrier();                                               \
    asm volatile("s_waitcnt lgkmcnt(0)" ::: "memory");                          \
    __builtin_amdgcn_sched_barrier(0);                                          \
    __builtin_amdgcn_s_setprio(1);                                              \
    _Pragma("unroll")                                                           \
    for (int m = 0; m < 4; ++m)                                                 \
      _Pragma("unroll")                                                         \
      for (int n = 0; n < 4; ++n)                                               \
        acc[(MH) * 4 + m][n] = MFMA16(af[m], bf[n][KS], acc[(MH) * 4 + m][n]);  \
    __builtin_amdgcn_s_setprio(0);                                              \
    TAIL;                                                                       \
    __builtin_amdgcn_sched_barrier(0);                                          \
    __builtin_amdgcn_s_barrier();                                               \
  } while (0)

  // Prologue: A(0), B(0), B(1); wait A(0)+B(0) (leave B(1)'s 4 in flight).
  STG_A(0, 0, 0); STG_A(0, 0, 1); STG_A(0, 1, 0); STG_A(0, 1, 1);
  STG_B(0, 0, 0); STG_B(0, 0, 1); STG_B(0, 1, 0); STG_B(0, 1, 1);
  STG_B(1, 0, 0); STG_B(1, 0, 1); STG_B(1, 1, 0); STG_B(1, 1, 1);
  VM4;
  __builtin_amdgcn_sched_barrier(0);
  __builtin_amdgcn_s_barrier();

  // Steady state. Iter i: compute tiles 2i (buf0), 2i+1 (buf1);
  // stage A(2i+1) @p0-1, B(2i+2) @p2-3, A(2i+2) @p4-5, B(2i+3) @p6-7.
  for (int i = 0; i < NI - 1; ++i) {
    const int tn = 2 * i;
    PH(0, 0, 0, 1, STG_A(tn + 1, 0, 0), STG_A(tn + 1, 0, 1), (void)0);
    PH(0, 0, 1, 1, STG_A(tn + 1, 1, 0), STG_A(tn + 1, 1, 1), (void)0);
    PH(0, 1, 0, 0, STG_B(tn + 2, 0, 0), STG_B(tn + 2, 0, 1), (void)0);
    PH(0, 1, 1, 0, STG_B(tn + 2, 1, 0), STG_B(tn + 2, 1, 1), VM4);
    PH(1, 0, 0, 1, STG_A(tn + 2, 0, 0), STG_A(tn + 2, 0, 1), (void)0);
    PH(1, 0, 1, 1, STG_A(tn + 2, 1, 0), STG_A(tn + 2, 1, 1), (void)0);
    PH(1, 1, 0, 0, STG_B(tn + 3, 0, 0), STG_B(tn + 3, 0, 1), (void)0);
    PH(1, 1, 1, 0, STG_B(tn + 3, 1, 0), STG_B(tn + 3, 1, 1), VM4);
  }
  // Last iter: only A(NC-1) still needed; drain fully at p3.
  {
    PH(0, 0, 0, 1, STG_A(NC - 1, 0, 0), STG_A(NC - 1, 0, 1), (void)0);
    PH(0, 0, 1, 1, STG_A(NC - 1, 1, 0), STG_A(NC - 1, 1, 1), (void)0);
    PH(0, 1, 0, 0, (void)0, (void)0, (void)0);
    PH(0, 1, 1, 0, (void)0, (void)0, VM0);
    PH(1, 0, 0, 1, (void)0, (void)0, (void)0);
    PH(1, 0, 1, 1, (void)0, (void)0, (void)0);
    PH(1, 1, 0, 0, (void)0, (void)0, (void)0);
    PH(1, 1, 1, 0, (void)0, (void)0, (void)0);
  }

#undef PH
#undef STG_A
#undef STG_B
#undef VM4
#undef VM0

  // C/D layout per 16x16 frag: col = lane&15, row = (lane>>4)*4 + j
#pragma unroll
  for (int m = 0; m < 8; ++m) {
    const int r0 = brow + wr * 128 + m * 16 + lg * 4;
#pragma unroll
    for (int n = 0; n < 4; ++n) {
      const int cc = bcol + wc * 64 + n * 16 + lr;
#pragma unroll
      for (int j = 0; j < 4; ++j)
        store_out(&C[(size_t)(r0 + j) * ldC + cc], acc[m][n][j]);
    }
  }
}

// ---------------- tiled transpose: out[c][r] = bf16(in[r][c]) ----------------
__global__ void trans_kernel(const float* __restrict__ in, u16* __restrict__ out, int n) {
  __shared__ float t[32][33];
  const int bx = (int)blockIdx.x * 32, by = (int)blockIdx.y * 32;
  const int x = (int)threadIdx.x, y0 = (int)threadIdx.y;
#pragma unroll
  for (int dy = 0; dy < 32; dy += 8)
    t[y0 + dy][x] = in[(size_t)(bx + y0 + dy) * n + by + x];
  __syncthreads();
#pragma unroll
  for (int dy = 0; dy < 32; dy += 8)
    out[(size_t)(by + y0 + dy) * n + bx + x] = f2bf(t[x][y0 + dy]);
}

// Qtp[c][perm(r)] = bf16(Q[r][c]); perm(r) = ((r&1)<<11)|(r>>1)
__global__ void transperm_kernel(const float* __restrict__ in, u16* __restrict__ out) {
  __shared__ float t[32][33];
  const int bx = (int)blockIdx.x * 32, by = (int)blockIdx.y * 32;
  const int x = (int)threadIdx.x, y0 = (int)threadIdx.y;
#pragma unroll
  for (int dy = 0; dy < 32; dy += 8)
    t[y0 + dy][x] = in[(size_t)(bx + y0 + dy) * 4096 + by + x];
  __syncthreads();
  const int r = bx + x;
  const int cp = ((r & 1) << 11) | (r >> 1);
#pragma unroll
  for (int dy = 0; dy < 32; dy += 8)
    out[(size_t)(by + y0 + dy) * 4096 + cp] = f2bf(t[x][y0 + dy]);
}

// rteff[i][j] = bf16(R[j][i] + D[i][j]);
// D[i][j] = c0(i,j)*(Dsub0+Dsub2)[i>>1][j>>1] + c1(i,j)*(Dsub1+Dsub3)[i>>1][j>>1]
__global__ void transadd_kernel(const float* __restrict__ R, const float* __restrict__ Dsub,
                                const float* __restrict__ R2, u16* __restrict__ out) {
  __shared__ float t[32][33];
  const int bx = (int)blockIdx.x * 32, by = (int)blockIdx.y * 32;
  const int x = (int)threadIdx.x, y0 = (int)threadIdx.y;
#pragma unroll
  for (int dy = 0; dy < 32; dy += 8)
    t[y0 + dy][x] = R[(size_t)(bx + y0 + dy) * 4096 + by + x];
  __syncthreads();
  const float r20 = R2[0], r21 = R2[1], r22 = R2[2], r23 = R2[3];
  const int j = bx + x;
  const float cj0 = (j & 1) ? r22 : r20;   // R2[j2][0]
  const float cj1 = (j & 1) ? r23 : r21;   // R2[j2][1]
#pragma unroll
  for (int dy = 0; dy < 32; dy += 8) {
    const int i = by + y0 + dy;
    const float ci0 = (i & 1) ? r22 : r20;
    const float ci1 = (i & 1) ? r23 : r21;
    const size_t o = ((size_t)(i >> 1) << 11) + (j >> 1);
    const float de = Dsub[o] + Dsub[o + 2u * 4194304u];
    const float dd = Dsub[o + 4194304u] + Dsub[o + 3u * 4194304u];
    const float d = ci0 * cj0 * de + ci1 * cj1 * dd;
    out[(size_t)i * 4096 + j] = f2bf(t[x][y0 + dy] + d);
  }
}

// Split-K layout: B2[kh][i1][kk] = bf16(R1[i1][kh*1024+kk]);
// A4[kh*2+p][i1][kk] = bf16(R1 .* lam_{e/o}) for parity p.
__global__ void scale_r1_kernel(const float* __restrict__ R1, const float* __restrict__ lam,
                                u16* __restrict__ B2, u16* __restrict__ A4) {
  const int idx = (int)blockIdx.x * 256 + (int)threadIdx.x;   // over 2048*512
  const int i1 = idx >> 9, k1 = (idx & 511) << 2;
  const float4 r1 = *(const float4*)(R1 + (size_t)i1 * 2048 + k1);
  const float4 l0 = *(const float4*)(lam + 2 * k1);
  const float4 l1 = *(const float4*)(lam + 2 * k1 + 4);
  const int kh = k1 >> 10, kk = k1 & 1023;
  const size_t off = (size_t)i1 * 1024 + kk;
  const size_t P = 2097152;   // plane elems (2048*1024)
  ushort4 rb, eb, ob;
  rb.x = f2bf(r1.x); rb.y = f2bf(r1.y); rb.z = f2bf(r1.z); rb.w = f2bf(r1.w);
  eb.x = f2bf(r1.x * l0.x); eb.y = f2bf(r1.y * l0.z);
  eb.z = f2bf(r1.z * l1.x); eb.w = f2bf(r1.w * l1.z);
  ob.x = f2bf(r1.x * l0.y); ob.y = f2bf(r1.y * l0.w);
  ob.z = f2bf(r1.z * l1.y); ob.w = f2bf(r1.w * l1.w);
  *(ushort4*)(B2 + (size_t)kh * P + off) = rb;
  *(ushort4*)(A4 + (size_t)(kh * 2) * P + off) = eb;
  *(ushort4*)(A4 + (size_t)(kh * 2 + 1) * P + off) = ob;
}

// T[j2][s][k1] = bf16(in[s][2k1]*Q2[0][j2] + in[s][2k1+1]*Q2[1][j2])
__global__ void tprep_kernel(const float* __restrict__ in, const float* __restrict__ Q2,
                             u16* __restrict__ T) {
  const int idx = (int)blockIdx.x * 256 + (int)threadIdx.x;   // over 4096*512
  const int s = idx >> 9, k1 = (idx & 511) << 2;
  const float4 a = *(const float4*)(in + (size_t)s * 4096 + 2 * k1);
  const float4 b = *(const float4*)(in + (size_t)s * 4096 + 2 * k1 + 4);
  const float e[4] = {a.x, a.z, b.x, b.z};
  const float o[4] = {a.y, a.w, b.y, b.w};
  const float q00 = Q2[0], q01 = Q2[1], q10 = Q2[2], q11 = Q2[3];
  ushort4 t0, t1;
  t0.x = f2bf(e[0] * q00 + o[0] * q10); t1.x = f2bf(e[0] * q01 + o[0] * q11);
  t0.y = f2bf(e[1] * q00 + o[1] * q10); t1.y = f2bf(e[1] * q01 + o[1] * q11);
  t0.z = f2bf(e[2] * q00 + o[2] * q10); t1.z = f2bf(e[2] * q01 + o[2] * q11);
  t0.w = f2bf(e[3] * q00 + o[3] * q10); t1.w = f2bf(e[3] * q01 + o[3] * q11);
  *(ushort4*)(T + (size_t)s * 2048 + k1) = t0;
  *(ushort4*)(T + 8388608 + (size_t)s * 2048 + k1) = t1;
}

extern "C" void kernel_launch(void* const* d_in, const int* in_sizes, int n_in,
                              void* d_out, int out_size, void* d_ws, size_t ws_size,
                              hipStream_t stream) {
  const float* input = (const float*)d_in[0];
  const float* Q     = (const float*)d_in[1];
  const float* R     = (const float*)d_in[2];
  const float* Q1    = (const float*)d_in[3];
  const float* Q2    = (const float*)d_in[4];
  const float* R1    = (const float*)d_in[5];
  const float* R2    = (const float*)d_in[6];
  const float* lam   = (const float*)d_in[7];
  float* out = (float*)d_out;

  const size_t MB = 1024ull * 1024ull;
  char* ws = (char*)d_ws;
  u16* B2    = (u16*)(ws + 0 * MB);     // 2 planes [2048][1024] bf16 (8MB)
  u16* A4    = (u16*)(ws + 8 * MB);     // 4 planes [2048][1024] bf16 (16MB)
  u16* Q1tb  = (u16*)(ws + 24 * MB);
  u16* T     = (u16*)(ws + 32 * MB);    // 2 planes of 16MB
  u16* Qtp   = (u16*)(ws + 64 * MB);
  u16* rteff = (u16*)(ws + 96 * MB);
  u16* X1p   = (u16*)(ws + 128 * MB);   // needs ws_size >= 160 MB
  u16* X2    = (u16*)(ws + 8 * MB);     // reuses A4/Q1tb/T-head (all dead by step 8)
  float* Dsub = (float*)d_out;          // 4 x 2048^2 f32 (64MB), consumed by transadd

  {
    void (*pf)(const u16*, const u16*, float*, int, int, int, int, long long, long long, long long) = gemm256<float>;
    void (*pb)(const u16*, const u16*, u16*, int, int, int, int, long long, long long, long long)   = gemm256<u16>;
    (void)hipFuncSetAttribute((const void*)pf, hipFuncAttributeMaxDynamicSharedMemorySize, 131072);
    (void)hipFuncSetAttribute((const void*)pb, hipFuncAttributeMaxDynamicSharedMemorySize, 131072);
  }

  const dim3 tb(32, 8);
  // 1) Q1tb = bf16(Q1^T)
  trans_kernel<<<dim3(64, 64), tb, 0, stream>>>(Q1, Q1tb, 2048);
  // 2) Qtp = permuted bf16(Q^T)
  transperm_kernel<<<dim3(128, 128), tb, 0, stream>>>(Q, Qtp);
  // 3) B2 + A4 split-K scaled copies
  scale_r1_kernel<<<4096, 256, 0, stream>>>(R1, lam, B2, A4);
  // 4) T[j2] = Q2-contraction of input
  tprep_kernel<<<8192, 256, 0, stream>>>(input, Q2, T);
  // 5) Dsub[z] = A4[z] @ B2[z>>1]^T   (split-K batched 4 x 2048x2048x1024, full grid)
  gemm256<float><<<dim3(8, 8, 4), 512, 131072, stream>>>(
      A4, B2, Dsub, 2048, 2048, 1024, 2048, 2097152LL, 2097152LL, 4194304LL);
  // 6) rteff = R^T + (c0*(D0+D2) + c1*(D1+D3) expanded via kron indices)
  transadd_kernel<<<dim3(128, 128), tb, 0, stream>>>(R, Dsub, R2, rteff);
  // 7) X1p[:, j2*2048+j1] = T[j2] @ Q1tb^T   (batched 2 x 4096x2048x2048)
  gemm256<u16><<<dim3(8, 16, 2), 512, 131072, stream>>>(
      T, Q1tb, X1p, 4096, 2048, 2048, 4096, 8388608LL, 0LL, 2048LL);
  // 8) X2 = X1p @ Qtp^T   (4096^3)
  gemm256<u16><<<dim3(16, 16, 1), 512, 131072, stream>>>(
      X1p, Qtp, X2, 4096, 4096, 4096, 4096, 0LL, 0LL, 0LL);
  // 9) out = X2 @ rteff^T  (4096^3, f32)
  gemm256<float><<<dim3(16, 16, 1), 512, 131072, stream>>>(
      X2, rteff, out, 4096, 4096, 4096, 4096, 0LL, 0LL, 0LL);
}

// Round 20
// 416.422 us; speedup vs baseline: 1.2259x; 1.0394x over previous
//
#include <hip/hip_runtime.h>
#include <stdint.h>

// KronQRInjectedLinear: out = ((input @ rot) @ Q) @ R_eff.
// Kron structure: rot via 2x4096x2048x2048 batched; D via TWO 2048^3 GEMMs (De/Do)
// with split-K z=4, partials summed in transadd. GEMM core: r16 measured-best
// (8-phase BK=64 2-dbuf, balanced 8/8/4/4 ds_reads, counted vmcnt, 0-conflict).
// r20: Dsub stored bf16 (D ~4e-8 << R, rounding invisible; -64MB traffic) and
// prep steps 1-4 fused into ONE launch (branch on block range; 9->6 launches).

typedef unsigned short u16;
typedef short bf16x8 __attribute__((ext_vector_type(8)));
typedef float f32x4 __attribute__((ext_vector_type(4)));

__device__ __forceinline__ u16 f2bf(float f) {
  union { float f; uint32_t u; } v; v.f = f;
  return (u16)((v.u + 0x7FFFu + ((v.u >> 16) & 1u)) >> 16);
}
__device__ __forceinline__ float bf2f(u16 v) {
  union { uint32_t u; float f; } c; c.u = (uint32_t)v << 16; return c.f;
}

__device__ __forceinline__ void store_out(float* p, float v) { *p = v; }
__device__ __forceinline__ void store_out(u16* p, float v) { *p = f2bf(v); }

__device__ __forceinline__ void gload_lds16(const u16* g, u16* l) {
  __builtin_amdgcn_global_load_lds(
      (__attribute__((address_space(1))) void*)(uintptr_t)g,
      (__attribute__((address_space(3))) void*)l, 16, 0, 0);
}

#define MFMA16(a, b, c) __builtin_amdgcn_mfma_f32_16x16x32_bf16((a), (b), (c), 0, 0, 0)

// -------- GEMM: C[M,N] = A[M,K] @ Bt[N,K]^T (batched: A += z*sA, Bt += (z>>1)*sB) --------
template <typename OutT>
__global__ __launch_bounds__(512, 2) void gemm256(
    const u16* __restrict__ A, const u16* __restrict__ Bt, OutT* __restrict__ C,
    int M, int N, int K, int ldC, long long sA, long long sB, long long sC) {
  extern __shared__ __align__(16) u16 smem[];
  u16* ldsA = smem;           // 2 bufs x 16384 elems (64 KB)
  u16* ldsB = smem + 32768;

  const int tid  = (int)threadIdx.x;
  const int lane = tid & 63;
  const int wid  = tid >> 6;
  const int wr   = wid >> 2;       // 0..1 : M half (128 rows)
  const int wc   = wid & 3;        // 0..3 : N quarter (64 cols)

  // XCD-aware bijective swizzle (nwg % 8 == 0 for all our grids)
  const int tilesX = (int)gridDim.x;
  const int tilesXY = tilesX * (int)gridDim.y;
  const int nwg = tilesXY * (int)gridDim.z;
  const int bid = ((int)blockIdx.z * (int)gridDim.y + (int)blockIdx.y) * tilesX + (int)blockIdx.x;
  const int swz = (bid & 7) * (nwg >> 3) + (bid >> 3);
  const int z   = swz / tilesXY;
  const int rem = swz % tilesXY;
  const int brow = (rem / tilesX) << 8;
  const int bcol = (rem % tilesX) << 8;
  A += (size_t)z * sA;
  Bt += (size_t)(z >> 1) * sB;
  C += (size_t)z * sC;

  // fragment-read lane constants (swizzled 16B slot is lane-constant)
  const int lr = lane & 15, lg = lane >> 4, h = lr >> 1;
  const int sf = (lg + ((lr & 1) << 2)) ^ h;
  const int abase = wr * 8192 + h * 64 + sf * 8;                    // + frag*512 + ks*4096 + buf*16384
  const int bbase = (wc >> 1) * 8192 + ((wc & 1) * 32 + h) * 64 + sf * 8;

  // staging: linear LDS dest (tid*16B within 8KB piece), inverse-swizzled source
  const int kp   = (tid & 7) ^ ((tid >> 3) & 7);
  const int srow = 2 * (tid >> 3) + (kp >> 2);
  const int scol = (kp & 3) << 3;
  const size_t gA0 = (size_t)(brow + srow) * K + scol;
  const size_t gB0 = (size_t)(bcol + srow) * K + scol;
  const size_t rstep = (size_t)K << 7;     // 128 rows
  const int sdst = wid * 512;

  const int NC = K >> 6;                   // 64-wide K-tiles (even, >= 4)
  const int NI = NC >> 1;

  f32x4 acc[8][4] = {};
  bf16x8 af[4], bf[4][2];

#define STG_A(t, rh, ks) gload_lds16(A + gA0 + (rh) * rstep + (size_t)(t) * 64 + (ks) * 32, \
    ldsA + ((t) & 1) * 16384 + (rh) * 8192 + (ks) * 4096 + sdst)
#define STG_B(t, rh, ks) gload_lds16(Bt + gB0 + (rh) * rstep + (size_t)(t) * 64 + (ks) * 32, \
    ldsB + ((t) & 1) * 16384 + (rh) * 8192 + (ks) * 4096 + sdst)
#define VM4 asm volatile("s_waitcnt vmcnt(4)" ::: "memory")
#define VM0 asm volatile("s_waitcnt vmcnt(0)" ::: "memory")

  // Phase (BUF, MH, KS): read af[m][KS] (4) and, if RDBF, bf[n][KS] (4) + 2 staged
  // pieces -> barrier -> lgkm(0) -> 16 MFMA -> tail -> barrier. Max 8 reads/phase.
#define PH(BUF, MH, KS, RDBF, S0, S1, TAIL) do {                                \
    const u16* _pa = ldsA + (BUF) * 16384 + abase + (KS) * 4096;                \
    const u16* _pb = ldsB + (BUF) * 16384 + bbase + (KS) * 4096;                \
    _Pragma("unroll")                                                           \
    for (int m = 0; m < 4; ++m)                                                 \
      af[m] = *(const bf16x8*)(_pa + ((MH) * 4 + m) * 512);                     \
    if (RDBF) {                                                                 \
      _Pragma("unroll")                                                         \
      for (int n = 0; n < 4; ++n)                                               \
        bf[n][KS] = *(const bf16x8*)(_pb + n * 512);                            \
    }                                                                           \
    S0; S1;                                                                     \
    __builtin_amdgcn_s_barrier();                                               \
    asm volatile("s_waitcnt lgkmcnt(0)" ::: "memory");                          \
    __builtin_amdgcn_sched_barrier(0);                                          \
    __builtin_amdgcn_s_setprio(1);                                              \
    _Pragma("unroll")                                                           \
    for (int m = 0; m < 4; ++m)                                                 \
      _Pragma("unroll")                                                         \
      for (int n = 0; n < 4; ++n)                                               \
        acc[(MH) * 4 + m][n] = MFMA16(af[m], bf[n][KS], acc[(MH) * 4 + m][n]);  \
    __builtin_amdgcn_s_setprio(0);                                              \
    TAIL;                                                                       \
    __builtin_amdgcn_sched_barrier(0);                                          \
    __builtin_amdgcn_s_barrier();                                               \
  } while (0)

  // Prologue: A(0), B(0), B(1); wait A(0)+B(0) (leave B(1)'s 4 in flight).
  STG_A(0, 0, 0); STG_A(0, 0, 1); STG_A(0, 1, 0); STG_A(0, 1, 1);
  STG_B(0, 0, 0); STG_B(0, 0, 1); STG_B(0, 1, 0); STG_B(0, 1, 1);
  STG_B(1, 0, 0); STG_B(1, 0, 1); STG_B(1, 1, 0); STG_B(1, 1, 1);
  VM4;
  __builtin_amdgcn_sched_barrier(0);
  __builtin_amdgcn_s_barrier();

  // Steady state. Iter i: compute tiles 2i (buf0), 2i+1 (buf1);
  // stage A(2i+1) @p0-1, B(2i+2) @p2-3, A(2i+2) @p4-5, B(2i+3) @p6-7.
  for (int i = 0; i < NI - 1; ++i) {
    const int tn = 2 * i;
    PH(0, 0, 0, 1, STG_A(tn + 1, 0, 0), STG_A(tn + 1, 0, 1), (void)0);
    PH(0, 0, 1, 1, STG_A(tn + 1, 1, 0), STG_A(tn + 1, 1, 1), (void)0);
    PH(0, 1, 0, 0, STG_B(tn + 2, 0, 0), STG_B(tn + 2, 0, 1), (void)0);
    PH(0, 1, 1, 0, STG_B(tn + 2, 1, 0), STG_B(tn + 2, 1, 1), VM4);
    PH(1, 0, 0, 1, STG_A(tn + 2, 0, 0), STG_A(tn + 2, 0, 1), (void)0);
    PH(1, 0, 1, 1, STG_A(tn + 2, 1, 0), STG_A(tn + 2, 1, 1), (void)0);
    PH(1, 1, 0, 0, STG_B(tn + 3, 0, 0), STG_B(tn + 3, 0, 1), (void)0);
    PH(1, 1, 1, 0, STG_B(tn + 3, 1, 0), STG_B(tn + 3, 1, 1), VM4);
  }
  // Last iter: only A(NC-1) still needed; drain fully at p3.
  {
    PH(0, 0, 0, 1, STG_A(NC - 1, 0, 0), STG_A(NC - 1, 0, 1), (void)0);
    PH(0, 0, 1, 1, STG_A(NC - 1, 1, 0), STG_A(NC - 1, 1, 1), (void)0);
    PH(0, 1, 0, 0, (void)0, (void)0, (void)0);
    PH(0, 1, 1, 0, (void)0, (void)0, VM0);
    PH(1, 0, 0, 1, (void)0, (void)0, (void)0);
    PH(1, 0, 1, 1, (void)0, (void)0, (void)0);
    PH(1, 1, 0, 0, (void)0, (void)0, (void)0);
    PH(1, 1, 1, 0, (void)0, (void)0, (void)0);
  }

#undef PH
#undef STG_A
#undef STG_B
#undef VM4
#undef VM0

  // C/D layout per 16x16 frag: col = lane&15, row = (lane>>4)*4 + j
#pragma unroll
  for (int m = 0; m < 8; ++m) {
    const int r0 = brow + wr * 128 + m * 16 + lg * 4;
#pragma unroll
    for (int n = 0; n < 4; ++n) {
      const int cc = bcol + wc * 64 + n * 16 + lr;
#pragma unroll
      for (int j = 0; j < 4; ++j)
        store_out(&C[(size_t)(r0 + j) * ldC + cc], acc[m][n][j]);
    }
  }
}

// -------- fused prep (steps 1-4): branch on block range, all independent --------
// [0,4096):       Q1tb = bf16(Q1^T)            (2048^2, tile grid 64x64)
// [4096,20480):   Qtp[c][perm(r)] = bf16(Q^T)  (4096^2, tile grid 128x128)
// [20480,24576):  B2/A4 split-K scaled copies of R1
// [24576,32768):  T[j2] = Q2-contraction of input
__global__ __launch_bounds__(256) void prep_all(
    const float* __restrict__ Q1, const float* __restrict__ Qm,
    const float* __restrict__ R1, const float* __restrict__ lam,
    const float* __restrict__ inp, const float* __restrict__ Q2,
    u16* __restrict__ Q1tb, u16* __restrict__ Qtp,
    u16* __restrict__ B2, u16* __restrict__ A4, u16* __restrict__ T) {
  __shared__ float t[32][33];
  const int bid = (int)blockIdx.x;
  const int tid = (int)threadIdx.x;
  if (bid < 4096) {
    const int bx = (bid & 63) * 32, by = (bid >> 6) * 32;
    const int x = tid & 31, y0 = tid >> 5;
#pragma unroll
    for (int dy = 0; dy < 32; dy += 8)
      t[y0 + dy][x] = Q1[(size_t)(bx + y0 + dy) * 2048 + by + x];
    __syncthreads();
#pragma unroll
    for (int dy = 0; dy < 32; dy += 8)
      Q1tb[(size_t)(by + y0 + dy) * 2048 + bx + x] = f2bf(t[x][y0 + dy]);
  } else if (bid < 20480) {
    const int b2 = bid - 4096;
    const int bx = (b2 & 127) * 32, by = (b2 >> 7) * 32;
    const int x = tid & 31, y0 = tid >> 5;
#pragma unroll
    for (int dy = 0; dy < 32; dy += 8)
      t[y0 + dy][x] = Qm[(size_t)(bx + y0 + dy) * 4096 + by + x];
    __syncthreads();
    const int r = bx + x;
    const int cp = ((r & 1) << 11) | (r >> 1);
#pragma unroll
    for (int dy = 0; dy < 32; dy += 8)
      Qtp[(size_t)(by + y0 + dy) * 4096 + cp] = f2bf(t[x][y0 + dy]);
  } else if (bid < 24576) {
    const int idx = (bid - 20480) * 256 + tid;   // over 2048*512
    const int i1 = idx >> 9, k1 = (idx & 511) << 2;
    const float4 r1 = *(const float4*)(R1 + (size_t)i1 * 2048 + k1);
    const float4 l0 = *(const float4*)(lam + 2 * k1);
    const float4 l1 = *(const float4*)(lam + 2 * k1 + 4);
    const int kh = k1 >> 10, kk = k1 & 1023;
    const size_t off = (size_t)i1 * 1024 + kk;
    const size_t P = 2097152;
    ushort4 rb, eb, ob;
    rb.x = f2bf(r1.x); rb.y = f2bf(r1.y); rb.z = f2bf(r1.z); rb.w = f2bf(r1.w);
    eb.x = f2bf(r1.x * l0.x); eb.y = f2bf(r1.y * l0.z);
    eb.z = f2bf(r1.z * l1.x); eb.w = f2bf(r1.w * l1.z);
    ob.x = f2bf(r1.x * l0.y); ob.y = f2bf(r1.y * l0.w);
    ob.z = f2bf(r1.z * l1.y); ob.w = f2bf(r1.w * l1.w);
    *(ushort4*)(B2 + (size_t)kh * P + off) = rb;
    *(ushort4*)(A4 + (size_t)(kh * 2) * P + off) = eb;
    *(ushort4*)(A4 + (size_t)(kh * 2 + 1) * P + off) = ob;
  } else {
    const int idx = (bid - 24576) * 256 + tid;   // over 4096*512
    const int s = idx >> 9, k1 = (idx & 511) << 2;
    const float4 a = *(const float4*)(inp + (size_t)s * 4096 + 2 * k1);
    const float4 b = *(const float4*)(inp + (size_t)s * 4096 + 2 * k1 + 4);
    const float e[4] = {a.x, a.z, b.x, b.z};
    const float o[4] = {a.y, a.w, b.y, b.w};
    const float q00 = Q2[0], q01 = Q2[1], q10 = Q2[2], q11 = Q2[3];
    ushort4 t0, t1;
    t0.x = f2bf(e[0] * q00 + o[0] * q10); t1.x = f2bf(e[0] * q01 + o[0] * q11);
    t0.y = f2bf(e[1] * q00 + o[1] * q10); t1.y = f2bf(e[1] * q01 + o[1] * q11);
    t0.z = f2bf(e[2] * q00 + o[2] * q10); t1.z = f2bf(e[2] * q01 + o[2] * q11);
    t0.w = f2bf(e[3] * q00 + o[3] * q10); t1.w = f2bf(e[3] * q01 + o[3] * q11);
    *(ushort4*)(T + (size_t)s * 2048 + k1) = t0;
    *(ushort4*)(T + 8388608 + (size_t)s * 2048 + k1) = t1;
  }
}

// rteff[i][j] = bf16(R[j][i] + D[i][j]);
// D[i][j] = c0(i,j)*(Dsub0+Dsub2)[i>>1][j>>1] + c1(i,j)*(Dsub1+Dsub3)[i>>1][j>>1]
// Dsub planes are bf16 (D ~4e-8 << R, rounding invisible).
__global__ void transadd_kernel(const float* __restrict__ R, const u16* __restrict__ Dsub,
                                const float* __restrict__ R2, u16* __restrict__ out) {
  __shared__ float t[32][33];
  const int bx = (int)blockIdx.x * 32, by = (int)blockIdx.y * 32;
  const int x = (int)threadIdx.x, y0 = (int)threadIdx.y;
#pragma unroll
  for (int dy = 0; dy < 32; dy += 8)
    t[y0 + dy][x] = R[(size_t)(bx + y0 + dy) * 4096 + by + x];
  __syncthreads();
  const float r20 = R2[0], r21 = R2[1], r22 = R2[2], r23 = R2[3];
  const int j = bx + x;
  const float cj0 = (j & 1) ? r22 : r20;   // R2[j2][0]
  const float cj1 = (j & 1) ? r23 : r21;   // R2[j2][1]
#pragma unroll
  for (int dy = 0; dy < 32; dy += 8) {
    const int i = by + y0 + dy;
    const float ci0 = (i & 1) ? r22 : r20;
    const float ci1 = (i & 1) ? r23 : r21;
    const size_t o = ((size_t)(i >> 1) << 11) + (j >> 1);
    const float de = bf2f(Dsub[o]) + bf2f(Dsub[o + 2u * 4194304u]);
    const float dd = bf2f(Dsub[o + 4194304u]) + bf2f(Dsub[o + 3u * 4194304u]);
    const float d = ci0 * cj0 * de + ci1 * cj1 * dd;
    out[(size_t)i * 4096 + j] = f2bf(t[x][y0 + dy] + d);
  }
}

extern "C" void kernel_launch(void* const* d_in, const int* in_sizes, int n_in,
                              void* d_out, int out_size, void* d_ws, size_t ws_size,
                              hipStream_t stream) {
  const float* input = (const float*)d_in[0];
  const float* Q     = (const float*)d_in[1];
  const float* R     = (const float*)d_in[2];
  const float* Q1    = (const float*)d_in[3];
  const float* Q2    = (const float*)d_in[4];
  const float* R1    = (const float*)d_in[5];
  const float* R2    = (const float*)d_in[6];
  const float* lam   = (const float*)d_in[7];
  float* out = (float*)d_out;

  const size_t MB = 1024ull * 1024ull;
  char* ws = (char*)d_ws;
  u16* B2    = (u16*)(ws + 0 * MB);     // 2 planes [2048][1024] bf16 (8MB)
  u16* A4    = (u16*)(ws + 8 * MB);     // 4 planes [2048][1024] bf16 (16MB)
  u16* Q1tb  = (u16*)(ws + 24 * MB);
  u16* T     = (u16*)(ws + 32 * MB);    // 2 planes of 16MB
  u16* Qtp   = (u16*)(ws + 64 * MB);
  u16* rteff = (u16*)(ws + 96 * MB);
  u16* X1p   = (u16*)(ws + 128 * MB);
  u16* Dsub  = (u16*)(ws + 160 * MB);   // 4 planes [2048][2048] bf16 (32MB); ws >= 192MB
  u16* X2    = (u16*)(ws + 8 * MB);     // reuses A4/Q1tb/T-head (all dead by step 8)

  {
    void (*pf)(const u16*, const u16*, float*, int, int, int, int, long long, long long, long long) = gemm256<float>;
    void (*pb)(const u16*, const u16*, u16*, int, int, int, int, long long, long long, long long)   = gemm256<u16>;
    (void)hipFuncSetAttribute((const void*)pf, hipFuncAttributeMaxDynamicSharedMemorySize, 131072);
    (void)hipFuncSetAttribute((const void*)pb, hipFuncAttributeMaxDynamicSharedMemorySize, 131072);
  }

  // 1) fused prep: Q1tb, Qtp, B2/A4, T
  prep_all<<<32768, 256, 0, stream>>>(Q1, Q, R1, lam, input, Q2, Q1tb, Qtp, B2, A4, T);
  // 2) Dsub[z] = A4[z] @ B2[z>>1]^T   (split-K batched 4 x 2048x2048x1024, bf16 out)
  gemm256<u16><<<dim3(8, 8, 4), 512, 131072, stream>>>(
      A4, B2, Dsub, 2048, 2048, 1024, 2048, 2097152LL, 2097152LL, 4194304LL);
  // 3) rteff = R^T + (c0*(D0+D2) + c1*(D1+D3) expanded via kron indices)
  transadd_kernel<<<dim3(128, 128), dim3(32, 8), 0, stream>>>(R, Dsub, R2, rteff);
  // 4) X1p[:, j2*2048+j1] = T[j2] @ Q1tb^T   (batched 2 x 4096x2048x2048)
  gemm256<u16><<<dim3(8, 16, 2), 512, 131072, stream>>>(
      T, Q1tb, X1p, 4096, 2048, 2048, 4096, 8388608LL, 0LL, 2048LL);
  // 5) X2 = X1p @ Qtp^T   (4096^3)
  gemm256<u16><<<dim3(16, 16, 1), 512, 131072, stream>>>(
      X1p, Qtp, X2, 4096, 4096, 4096, 4096, 0LL, 0LL, 0LL);
  // 6) out = X2 @ rteff^T  (4096^3, f32)
  gemm256<float><<<dim3(16, 16, 1), 512, 131072, stream>>>(
      X2, rteff, out, 4096, 4096, 4096, 4096, 0LL, 0LL, 0LL);
}